// Round 2
// baseline (133.653 us; speedup 1.0000x reference)
//
#include <hip/hip_runtime.h>
#include <hip/hip_cooperative_groups.h>

namespace cg = cooperative_groups;

// Problem constants (match reference)
#define TT 512   // sequence length
#define DD 256   // in_vocab_size
#define HH 256   // hidden_size

// Decomposition: CC chunks of LL steps; each chunk's GEMM+scan is split
// across USPLIT unit-groups (blocks) and KSPLIT K-slices (lanes).
// 256 blocks x 256 threads = 1 block/CU -> trivially co-resident, so a
// cooperative grid sync is safe. Fusing chunk+fixup removes one dispatch,
// the inter-kernel drain, and the 2 MB out read-modify-write (local scan
// values stay in registers across the sync).
#define CC 32
#define LL (TT / CC)        // 16 steps per chunk
#define USPLIT 8            // unit groups per chunk
#define UPB (HH / USPLIT)   // 32 units per block
#define KSPLIT 8            // K slices per unit
#define KW (DD / KSPLIT)    // 32 floats per K slice

// Per-unit recurrence: h = (h1 + i h2); step: h' = r h + g*bx,
// r = c + i s, c = y cos z, s = y sin z, y = exp(-exp(lamda)), z = exp(theta),
// g = sqrt(1 - y^2). Only concat(h1,h2) is observable output; all RTRL
// sensitivity state in the reference is dead code (never reaches the output).
__device__ inline void coeffs(const float* __restrict__ lamda,
                              const float* __restrict__ theta, int j,
                              float& c, float& s, float& g) {
  const float y = __expf(-__expf(lamda[j]));
  const float z = __expf(theta[j]);
  c = y * __cosf(z);
  s = y * __sinf(z);
  g = sqrtf(fmaxf(1.0f - y * y, 0.0f));
}

// Fused kernel. Block (cidx,q): units u in [q*32,(q+1)*32), t in
// [cidx*16,(cidx+1)*16). Thread = (unit, K-slice).
// Phase 1: GEMM partials (registers) + shfl_xor combine + local scan with
//          zero carry; each lane keeps its 2 owned steps' h in registers;
//          chunk-end state -> E; threadfence.
// grid.sync()
// Phase 2: redundant per-block carry S_c = sum_{ci<c} (r^LL)^{c-1-ci} E[ci]
//          (<=31 chained complex FMAs), then out = local + r^(i+1)*S_c,
//          written exactly once per (t, unit).
__global__ __launch_bounds__(256) void rtu_fused(
    const float* __restrict__ x, const float* __restrict__ lamda,
    const float* __restrict__ theta, const float* __restrict__ B1,
    const float* __restrict__ B2, float* __restrict__ out,
    float* __restrict__ E) {
  __shared__ float xs[LL * DD];  // 16 KB
  const int cidx = blockIdx.x >> 3;          // chunk
  const int q = blockIdx.x & (USPLIT - 1);   // unit group
  const int t0 = cidx * LL;
  const int tid = threadIdx.x;
  const int ul = tid >> 3;                   // unit within group (0..31)
  const int kq = tid & (KSPLIT - 1);         // K slice (0..7)
  const int u = q * UPB + ul;                // global unit

  // Prefetch this thread's B slices into registers BEFORE the staging
  // barrier (compiler can't hoist global loads across s_barrier). The
  // bank-rotation (+kq) is applied to the GLOBAL load address so the
  // register array index stays compile-time (no scratch spill).
  const float4* b1 = (const float4*)(B1 + u * DD + kq * KW);
  const float4* b2 = (const float4*)(B2 + u * DD + kq * KW);
  float4 rb1[KW / 4], rb2[KW / 4];
#pragma unroll
  for (int k4 = 0; k4 < KW / 4; ++k4) {
    const int kk = (k4 + kq) & (KW / 4 - 1);
    rb1[k4] = b1[kk];
    rb2[k4] = b2[kk];
  }

  // Stage this chunk's 16 x-rows (16 KB) into LDS: 4 float4s per thread.
  {
    const float4* xsrc = (const float4*)(x + t0 * DD);
    float4* xdst = (float4*)xs;
#pragma unroll
    for (int p = 0; p < (LL * DD / 4) / 256; ++p)
      xdst[p * 256 + tid] = xsrc[p * 256 + tid];
  }
  __syncthreads();

  const float4* xs4 = (const float4*)xs;

  float a1[LL], a2[LL];
#pragma unroll
  for (int tt = 0; tt < LL; ++tt) { a1[tt] = 0.f; a2[tt] = 0.f; }

#pragma unroll
  for (int k4 = 0; k4 < KW / 4; ++k4) {
    // Rotated LDS read order: the 8 broadcast reads of a wave sit at
    // 32-word stride (all bank 0 unrotated); +kq spreads them across
    // banks 0..31 -> conflict-free. rb1[k4] holds exactly column group kk.
    const int kk = (k4 + kq) & (KW / 4 - 1);
    const float4 v1 = rb1[k4];
    const float4 v2 = rb2[k4];
#pragma unroll
    for (int tt = 0; tt < LL; ++tt) {
      const float4 xv = xs4[tt * (DD / 4) + kq * (KW / 4) + kk];
      a1[tt] = fmaf(v1.x, xv.x, a1[tt]);
      a1[tt] = fmaf(v1.y, xv.y, a1[tt]);
      a1[tt] = fmaf(v1.z, xv.z, a1[tt]);
      a1[tt] = fmaf(v1.w, xv.w, a1[tt]);
      a2[tt] = fmaf(v2.x, xv.x, a2[tt]);
      a2[tt] = fmaf(v2.y, xv.y, a2[tt]);
      a2[tt] = fmaf(v2.z, xv.z, a2[tt]);
      a2[tt] = fmaf(v2.w, xv.w, a2[tt]);
    }
  }

  // Combine the 8 K-slice partials (lanes of one unit differ in bits 0..2).
#pragma unroll
  for (int tt = 0; tt < LL; ++tt) {
    float r1 = a1[tt], r2 = a2[tt];
    r1 += __shfl_xor(r1, 1);
    r1 += __shfl_xor(r1, 2);
    r1 += __shfl_xor(r1, 4);
    r2 += __shfl_xor(r2, 1);
    r2 += __shfl_xor(r2, 2);
    r2 += __shfl_xor(r2, 4);
    a1[tt] = r1;
    a2[tt] = r2;
  }

  float c, s, g;
  coeffs(lamda, theta, u, c, s, g);

  // Local scan (carry-in = 0). All 8 lanes of a unit compute redundantly;
  // lane kq keeps steps {2kq, 2kq+1} in registers for phase 2.
  float h1 = 0.f, h2 = 0.f;
  float l1a = 0.f, l2a = 0.f, l1b = 0.f, l2b = 0.f;
#pragma unroll
  for (int tt = 0; tt < LL; ++tt) {
    const float bb1 = a1[tt] * g;
    const float bb2 = a2[tt] * g;
    const float n1 = fmaf(c, h1, fmaf(-s, h2, bb1));
    const float n2 = fmaf(c, h2, fmaf(s, h1, bb2));
    h1 = n1;
    h2 = n2;
    if (kq == (tt >> 1)) {
      if (tt & 1) { l1b = h1; l2b = h2; }
      else        { l1a = h1; l2a = h2; }
    }
  }
  if (kq == 0) E[cidx * (2 * HH) + u] = h1;
  if (kq == 1) E[cidx * (2 * HH) + HH + u] = h2;

  // Cross-XCD visibility of E: device-scope release, grid barrier, acquire.
  __threadfence();
  cg::this_grid().sync();
  __threadfence();

  // r^LL, LL = 16 -> 4 complex squarings (exact composition of the step op).
  float cl = c, sl = s;
#pragma unroll
  for (int qq = 0; qq < 4; ++qq) {
    const float nc = cl * cl - sl * sl;
    const float ns = 2.f * cl * sl;
    cl = nc;
    sl = ns;
  }

  // Carry chain (<=31 dependent complex FMAs; cidx==0 does zero iters).
  float S1 = 0.f, S2 = 0.f;
  const float* Ep = E + u;
#pragma unroll 8
  for (int ci = 0; ci < cidx; ++ci) {
    const float E1 = Ep[ci * (2 * HH)];
    const float E2 = Ep[ci * (2 * HH) + HH];
    const float n1 = fmaf(cl, S1, fmaf(-sl, S2, E1));
    const float n2 = fmaf(cl, S2, fmaf(sl, S1, E2));
    S1 = n1;
    S2 = n2;
  }

  // Sequential powers r^(i+1) (identical mul order to the old fixup);
  // capture the two owned powers.
  float p1 = c, p2 = s;
  float pa1 = 0.f, pa2 = 0.f, pb1 = 0.f, pb2 = 0.f;
#pragma unroll
  for (int i = 0; i < LL; ++i) {
    if (kq == (i >> 1)) {
      if (i & 1) { pb1 = p1; pb2 = p2; }
      else       { pa1 = p1; pa2 = p2; }
    }
    const float np1 = p1 * c - p2 * s;
    const float np2 = p1 * s + p2 * c;
    p1 = np1;
    p2 = np2;
  }

  // Final, single write of out for the two owned steps.
  const int ta = t0 + 2 * kq;
  out[ta * (2 * HH) + u]            = l1a + pa1 * S1 - pa2 * S2;
  out[ta * (2 * HH) + HH + u]       = l2a + pa2 * S1 + pa1 * S2;
  out[(ta + 1) * (2 * HH) + u]      = l1b + pb1 * S1 - pb2 * S2;
  out[(ta + 1) * (2 * HH) + HH + u] = l2b + pb2 * S1 + pb1 * S2;
}

extern "C" void kernel_launch(void* const* d_in, const int* in_sizes, int n_in,
                              void* d_out, int out_size, void* d_ws, size_t ws_size,
                              hipStream_t stream) {
  const float* x     = (const float*)d_in[0];  // [T, D]
  const float* lamda = (const float*)d_in[1];  // [H]
  const float* theta = (const float*)d_in[2];  // [H]
  const float* B1    = (const float*)d_in[3];  // [H, D]
  const float* B2    = (const float*)d_in[4];  // [H, D]
  float* out = (float*)d_out;                  // [T, 2H]

  float* E = (float*)d_ws;                     // [CC, 2H] (64 KB)

  void* args[] = {(void*)&x, (void*)&lamda, (void*)&theta,
                  (void*)&B1, (void*)&B2, (void*)&out, (void*)&E};
  hipLaunchCooperativeKernel((const void*)rtu_fused, dim3(CC * USPLIT),
                             dim3(256), args, 0, stream);
}

// Round 4
// 77.558 us; speedup vs baseline: 1.7233x; 1.7233x over previous
//
#include <hip/hip_runtime.h>

// Problem constants (match reference)
#define TT 512   // sequence length
#define DD 256   // in_vocab_size
#define HH 256   // hidden_size

// Decomposition: CC chunks of LL steps; each chunk's GEMM+scan is split
// across USPLIT unit-groups (blocks) and KSPLIT K-slices (lanes).
//  - B re-read traffic = CC * 512KB = 16MB through L2 (vs 64MB at CC=128)
//  - grid 256 blocks -> all 256 CUs busy
//  - per-thread serial FMA: 1024 (K split 8-way, shfl_xor combine)
//  - fixup carry chain: <=31 dependent complex FMAs
// NOTE (round-2 lesson): do NOT fuse these with a cooperative grid sync —
// cg::this_grid().sync() measured ~50us on MI355X (cross-XCD atomic spin),
// vs ~1-2us for the second dispatch.
#define CC 32
#define LL (TT / CC)        // 16 steps per chunk
#define USPLIT 8            // unit groups per chunk
#define UPB (HH / USPLIT)   // 32 units per block
#define KSPLIT 8            // K slices per unit
#define KW (DD / KSPLIT)    // 32 floats per K slice

// Per-unit recurrence: h = (h1 + i h2); step: h' = r h + g*bx,
// r = c + i s, c = y cos z, s = y sin z, y = exp(-exp(lamda)), z = exp(theta),
// g = sqrt(1 - y^2). Only concat(h1,h2) is observable output; all RTRL
// sensitivity state in the reference is dead code (never reaches the output).
__device__ inline void coeffs(const float* __restrict__ lamda,
                              const float* __restrict__ theta, int j,
                              float& c, float& s, float& g) {
  const float y = __expf(-__expf(lamda[j]));
  const float z = __expf(theta[j]);
  c = y * __cosf(z);
  s = y * __sinf(z);
  g = sqrtf(fmaxf(1.0f - y * y, 0.0f));
}

// Kernel 1: per-(chunk, unit-group) GEMM + local scan, register-resident.
// Block (cidx,q): units u in [q*32,(q+1)*32), t in [cidx*16,(cidx+1)*16).
// Thread = (unit, K-slice): accumulates a partial dot over its 32 K columns,
// then a 3-level shfl_xor tree (lanes differing in bits 0..2) produces the
// full Bx sums in all 8 lanes of the unit's octet. All 8 lanes run the tiny
// local scan redundantly; stores are ownership-split so each (t,unit) is
// written once. Bx is never materialized to memory.
__global__ __launch_bounds__(256) void rtu_chunk(
    const float* __restrict__ x, const float* __restrict__ lamda,
    const float* __restrict__ theta, const float* __restrict__ B1,
    const float* __restrict__ B2, float* __restrict__ out,
    float* __restrict__ E) {
  __shared__ float xs[LL * DD];  // 16 KB
  const int cidx = blockIdx.x >> 3;          // chunk
  const int q = blockIdx.x & (USPLIT - 1);   // unit group
  const int t0 = cidx * LL;
  const int tid = threadIdx.x;
  const int ul = tid >> 3;                   // unit within group (0..31)
  const int kq = tid & (KSPLIT - 1);         // K slice (0..7)
  const int u = q * UPB + ul;                // global unit

  // Stage this chunk's 16 x-rows (16 KB) into LDS: 4 float4s per thread.
  {
    const float4* xsrc = (const float4*)(x + t0 * DD);
    float4* xdst = (float4*)xs;
#pragma unroll
    for (int p = 0; p < (LL * DD / 4) / 256; ++p)
      xdst[p * 256 + tid] = xsrc[p * 256 + tid];
  }
  __syncthreads();

  const float4* b1 = (const float4*)(B1 + u * DD + kq * KW);
  const float4* b2 = (const float4*)(B2 + u * DD + kq * KW);
  const float4* xs4 = (const float4*)xs;

  float a1[LL], a2[LL];
#pragma unroll
  for (int tt = 0; tt < LL; ++tt) { a1[tt] = 0.f; a2[tt] = 0.f; }

#pragma unroll
  for (int k4 = 0; k4 < KW / 4; ++k4) {
    // Rotate the k4 order per K-slice: the 8 broadcast LDS reads of a wave
    // sit at 32-word stride (all bank 0 unrotated); the +kq rotation spreads
    // them across banks 0..31 -> conflict-free.
    const int kk = (k4 + kq) & (KW / 4 - 1);
    const float4 v1 = b1[kk];
    const float4 v2 = b2[kk];
#pragma unroll
    for (int tt = 0; tt < LL; ++tt) {
      const float4 xv = xs4[tt * (DD / 4) + kq * (KW / 4) + kk];
      a1[tt] = fmaf(v1.x, xv.x, a1[tt]);
      a1[tt] = fmaf(v1.y, xv.y, a1[tt]);
      a1[tt] = fmaf(v1.z, xv.z, a1[tt]);
      a1[tt] = fmaf(v1.w, xv.w, a1[tt]);
      a2[tt] = fmaf(v2.x, xv.x, a2[tt]);
      a2[tt] = fmaf(v2.y, xv.y, a2[tt]);
      a2[tt] = fmaf(v2.z, xv.z, a2[tt]);
      a2[tt] = fmaf(v2.w, xv.w, a2[tt]);
    }
  }

  // Combine the 8 K-slice partials (lanes of one unit differ in bits 0..2).
#pragma unroll
  for (int tt = 0; tt < LL; ++tt) {
    float r1 = a1[tt], r2 = a2[tt];
    r1 += __shfl_xor(r1, 1);
    r1 += __shfl_xor(r1, 2);
    r1 += __shfl_xor(r1, 4);
    r2 += __shfl_xor(r2, 1);
    r2 += __shfl_xor(r2, 2);
    r2 += __shfl_xor(r2, 4);
    a1[tt] = r1;
    a2[tt] = r2;
  }

  float c, s, g;
  coeffs(lamda, theta, u, c, s, g);

  // Local scan (carry-in = 0); uncorrected outputs + chunk-end state.
  // All 8 lanes of a unit compute redundantly (16 steps x 4 fma — cheap);
  // lane kq stores steps {2kq, 2kq+1} so every (t,unit) is written once.
  float h1 = 0.f, h2 = 0.f;
#pragma unroll
  for (int tt = 0; tt < LL; ++tt) {
    const float bb1 = a1[tt] * g;
    const float bb2 = a2[tt] * g;
    const float n1 = fmaf(c, h1, fmaf(-s, h2, bb1));
    const float n2 = fmaf(c, h2, fmaf(s, h1, bb2));
    h1 = n1;
    h2 = n2;
    if (kq == (tt >> 1)) {
      out[(t0 + tt) * (2 * HH) + u] = h1;
      out[(t0 + tt) * (2 * HH) + HH + u] = h2;
    }
  }
  if (kq == 0) E[cidx * (2 * HH) + u] = h1;
  if (kq == 1) E[cidx * (2 * HH) + HH + u] = h2;
}

// Kernel 2: fused combine + correct. Block c (c>=1) redundantly computes its
// own carry S_c = sum_{ci<c} (r^LL)^{c-1-ci} E[ci] via a chained complex FMA
// (<=31 steps; loads independent, chain ~8 cyc/step), then applies
// out[t0+i] += r^(i+1) * S_c in place. No grid sync, no carry round-trip.
__global__ __launch_bounds__(256) void rtu_fixup(
    const float* __restrict__ lamda, const float* __restrict__ theta,
    const float* __restrict__ E, float* __restrict__ out) {
  const int cidx = blockIdx.x + 1;  // chunk 0 needs no correction
  const int j = threadIdx.x;
  float c, s, g;
  coeffs(lamda, theta, j, c, s, g);

  // r^LL, LL = 16 -> 4 complex squarings (exact composition of the step op).
  float cl = c, sl = s;
#pragma unroll
  for (int qq = 0; qq < 4; ++qq) {
    const float nc = cl * cl - sl * sl;
    const float ns = 2.f * cl * sl;
    cl = nc;
    sl = ns;
  }

  float S1 = 0.f, S2 = 0.f;
  const float* Ep = E + j;
#pragma unroll 8
  for (int ci = 0; ci < cidx; ++ci) {
    const float E1 = Ep[ci * (2 * HH)];
    const float E2 = Ep[ci * (2 * HH) + HH];
    const float n1 = fmaf(cl, S1, fmaf(-sl, S2, E1));
    const float n2 = fmaf(cl, S2, fmaf(sl, S1, E2));
    S1 = n1;
    S2 = n2;
  }

  const int t0 = cidx * LL;
  float p1 = c, p2 = s;  // r^(i+1)
#pragma unroll
  for (int i = 0; i < LL; ++i) {
    const int t = t0 + i;
    const float o1 = out[t * (2 * HH) + j] + p1 * S1 - p2 * S2;
    const float o2 = out[t * (2 * HH) + HH + j] + p2 * S1 + p1 * S2;
    out[t * (2 * HH) + j] = o1;
    out[t * (2 * HH) + HH + j] = o2;
    const float np1 = p1 * c - p2 * s;
    const float np2 = p1 * s + p2 * c;
    p1 = np1;
    p2 = np2;
  }
}

extern "C" void kernel_launch(void* const* d_in, const int* in_sizes, int n_in,
                              void* d_out, int out_size, void* d_ws, size_t ws_size,
                              hipStream_t stream) {
  const float* x     = (const float*)d_in[0];  // [T, D]
  const float* lamda = (const float*)d_in[1];  // [H]
  const float* theta = (const float*)d_in[2];  // [H]
  const float* B1    = (const float*)d_in[3];  // [H, D]
  const float* B2    = (const float*)d_in[4];  // [H, D]
  float* out = (float*)d_out;                  // [T, 2H]

  float* E = (float*)d_ws;                     // [CC, 2H] (64 KB)

  rtu_chunk<<<dim3(CC * USPLIT), 256, 0, stream>>>(x, lamda, theta, B1, B2,
                                                   out, E);
  rtu_fixup<<<dim3(CC - 1), 256, 0, stream>>>(lamda, theta, E, out);
}